// Round 5
// baseline (518.147 us; speedup 1.0000x reference)
//
#include <hip/hip_runtime.h>
#include <hip/hip_bf16.h>
#include <cstdint>
#include <cstddef>

// ---------------- problem constants ----------------
#define DTOK 1024      // embed dim
#define IFF  512       // ffn intermediate
#define NEXP 7         // routed experts
#define TTOK 16384     // B*S tokens
#define CAP  (2*TTOK + NEXP*256)   // padded routed slot capacity = 34560 (135 tiles of 256)
#define CAPX (CAP + TTOK)          // + shared segment (expert 7, identity) = 50944

typedef __bf16 v8bf  __attribute__((ext_vector_type(8)));
typedef float  f32x4 __attribute__((ext_vector_type(4)));

#define AS1 __attribute__((address_space(1)))
#define AS3 __attribute__((address_space(3)))

// ---------------- small prep kernels ----------------

// slots [0,CAP): routed (filled by gather); [CAP,CAPX): shared expert, identity map, w=1
__global__ void init_kernel(int* __restrict__ slot_token, float* __restrict__ slot_w,
                            __bf16* __restrict__ zpage) {
    int i = blockIdx.x * 256 + threadIdx.x;
    if (i < CAP) slot_token[i] = -1;
    else if (i < CAPX) { slot_token[i] = i - CAP; slot_w[i] = 1.f; }
    if (i < 2048) zpage[i] = (__bf16)0.f;
}

__global__ void cast_x_kernel(const float4* __restrict__ x, __bf16* __restrict__ xb) {
    int i = blockIdx.x * 256 + threadIdx.x;   // one float4 per thread
    float4 v = x[i];
    typedef __bf16 v4bf __attribute__((ext_vector_type(4)));
    v4bf o; o[0] = (__bf16)v.x; o[1] = (__bf16)v.y; o[2] = (__bf16)v.z; o[3] = (__bf16)v.w;
    *reinterpret_cast<v4bf*>(xb + (size_t)i * 4) = o;
}

// B1[e][r][k] = W[k][c], c=(r>>5)*16+(r&15), gate if (r&31)<16 else up.
// Coalesced via LDS transpose. block = (kh in [0,2), j in [0,32), e in [0,8))
__global__ __launch_bounds__(256) void build_B1t(
    const float* __restrict__ r_gate, const float* __restrict__ r_up,
    const float* __restrict__ sh_gate, const float* __restrict__ sh_up,
    __bf16* __restrict__ B1) {
    const int kh = blockIdx.x, j = blockIdx.y, e = blockIdx.z;
    const float* G = (e < NEXP) ? (r_gate + (size_t)e * (DTOK * IFF)) : sh_gate;
    const float* U = (e < NEXP) ? (r_up   + (size_t)e * (DTOK * IFF)) : sh_up;
    __shared__ __bf16 lg[16][520];
    __shared__ __bf16 lu[16][520];
    const int tid = threadIdx.x;
    const int c4 = tid & 3, kk0 = tid >> 2;
    #pragma unroll
    for (int p = 0; p < 8; ++p) {
        int kk = kk0 + p * 64;
        size_t off = (size_t)(kh * 512 + kk) * IFF + j * 16 + c4 * 4;
        float4 g = *(const float4*)&G[off];
        float4 u = *(const float4*)&U[off];
        lg[c4*4+0][kk] = (__bf16)g.x; lg[c4*4+1][kk] = (__bf16)g.y;
        lg[c4*4+2][kk] = (__bf16)g.z; lg[c4*4+3][kk] = (__bf16)g.w;
        lu[c4*4+0][kk] = (__bf16)u.x; lu[c4*4+1][kk] = (__bf16)u.y;
        lu[c4*4+2][kk] = (__bf16)u.z; lu[c4*4+3][kk] = (__bf16)u.w;
    }
    __syncthreads();
    const int rr = tid >> 3;
    const int ch0 = tid & 7;
    const int cc = rr & 15;
    const bool isup = rr >= 16;
    const int r = j * 32 + (isup ? 16 : 0) + cc;
    const __bf16* src = isup ? &lu[cc][0] : &lg[cc][0];
    __bf16* dst = B1 + ((size_t)e << 20) + (size_t)r * DTOK + kh * 512;
    #pragma unroll
    for (int q = 0; q < 8; ++q) {
        int ch = ch0 + q * 8;
        *(v8bf*)&dst[ch * 8] = *(const v8bf*)&src[ch * 8];
    }
}

// B2[e][n][k] = down[k][n]. block = (kh in [0,2), nb in [0,16), e in [0,8))
__global__ __launch_bounds__(256) void build_B2t(
    const float* __restrict__ r_down, const float* __restrict__ sh_down,
    __bf16* __restrict__ B2) {
    const int kh = blockIdx.x, nb = blockIdx.y, e = blockIdx.z;
    const float* D = (e < NEXP) ? (r_down + (size_t)e * (IFF * DTOK)) : sh_down;
    __shared__ __bf16 ln[64][264];
    const int tid = threadIdx.x;
    const int c4 = tid & 15, kk0 = tid >> 4;
    #pragma unroll
    for (int p = 0; p < 16; ++p) {
        int kk = kk0 + p * 16;
        size_t off = (size_t)(kh * 256 + kk) * DTOK + nb * 64 + c4 * 4;
        float4 v = *(const float4*)&D[off];
        ln[c4*4+0][kk] = (__bf16)v.x; ln[c4*4+1][kk] = (__bf16)v.y;
        ln[c4*4+2][kk] = (__bf16)v.z; ln[c4*4+3][kk] = (__bf16)v.w;
    }
    __syncthreads();
    const int nn = tid >> 2;
    const int ch0 = tid & 3;
    __bf16* dst = B2 + ((size_t)e * 1024 + nb * 64 + nn) * IFF + kh * 256;
    #pragma unroll
    for (int q = 0; q < 8; ++q) {
        int ch = ch0 + q * 4;
        *(v8bf*)&dst[ch * 8] = *(const v8bf*)&ln[nn][ch * 8];
    }
}

// Router: full fp32 (bf16 x would flip near-tie top-k picks -> real output error).
__global__ __launch_bounds__(256) void router_kernel(
    const float* __restrict__ x, const float* __restrict__ w_r,
    const float* __restrict__ b_r, const float* __restrict__ rb,
    int* __restrict__ top_i, float* __restrict__ top_w) {
    int wid = threadIdx.x >> 6, lane = threadIdx.x & 63;
    int t = blockIdx.x * 4 + wid;
    float acc[NEXP] = {0.f,0.f,0.f,0.f,0.f,0.f,0.f};
    #pragma unroll 4
    for (int it = 0; it < DTOK / 64; ++it) {
        int d = it * 64 + lane;
        float xv = x[(size_t)t * DTOK + d];
        const float* wr = w_r + (size_t)d * NEXP;
        #pragma unroll
        for (int e = 0; e < NEXP; ++e) acc[e] += xv * wr[e];
    }
    #pragma unroll
    for (int e = 0; e < NEXP; ++e)
        #pragma unroll
        for (int off = 32; off; off >>= 1) acc[e] += __shfl_xor(acc[e], off);
    if (lane == 0) {
        float p[NEXP];
        #pragma unroll
        for (int e = 0; e < NEXP; ++e) p[e] = 1.f / (1.f + expf(-(acc[e] + b_r[e] + rb[e])));
        int i0 = 0;
        #pragma unroll
        for (int e = 1; e < NEXP; ++e) if (p[e] > p[i0]) i0 = e;
        int i1 = -1;
        #pragma unroll
        for (int e = 0; e < NEXP; ++e) if (e != i0 && (i1 < 0 || p[e] > p[i1])) i1 = e;
        float s = p[i0] + p[i1];
        top_i[2 * t] = i0; top_i[2 * t + 1] = i1;
        top_w[2 * t] = p[i0] / s; top_w[2 * t + 1] = p[i1] / s;
    }
}

// Deterministic atomic-free gather build (scan). Segments padded to 256 rows.
__global__ __launch_bounds__(1024) void gather_kernel(
    const int* __restrict__ top_i, const float* __restrict__ top_w,
    int* __restrict__ slot_token, float* __restrict__ slot_w,
    int* __restrict__ tok_slot, int* __restrict__ offs_out) {
    __shared__ int h[NEXP][1024];
    __shared__ int lofs[NEXP];
    const int tid = threadIdx.x;
    const int base = tid * 32;

    int cnt[NEXP] = {0,0,0,0,0,0,0};
    int emem[32];
    float wmem[32];
    #pragma unroll
    for (int j = 0; j < 32; ++j) {
        emem[j] = top_i[base + j];
        wmem[j] = top_w[base + j];
        #pragma unroll
        for (int q = 0; q < NEXP; ++q) if (emem[j] == q) cnt[q]++;
    }
    #pragma unroll
    for (int q = 0; q < NEXP; ++q) h[q][tid] = cnt[q];
    __syncthreads();
    for (int off = 1; off < 1024; off <<= 1) {
        int v[NEXP];
        #pragma unroll
        for (int q = 0; q < NEXP; ++q) v[q] = (tid >= off) ? h[q][tid - off] : 0;
        __syncthreads();
        #pragma unroll
        for (int q = 0; q < NEXP; ++q) h[q][tid] += v[q];
        __syncthreads();
    }
    if (tid == 0) {
        int o = 0;
        #pragma unroll
        for (int q = 0; q < NEXP; ++q) { lofs[q] = o; o += ((h[q][1023] + 255) >> 8) << 8; }
        #pragma unroll
        for (int q = 0; q < NEXP; ++q) offs_out[q] = lofs[q];
        offs_out[NEXP] = CAP;   // expert 7 = shared segment
    }
    __syncthreads();
    int pos[NEXP];
    #pragma unroll
    for (int q = 0; q < NEXP; ++q) pos[q] = lofs[q] + h[q][tid] - cnt[q];
    #pragma unroll
    for (int j = 0; j < 32; ++j) {
        int t = (base + j) >> 1;
        #pragma unroll
        for (int q = 0; q < NEXP; ++q) if (emem[j] == q) {
            slot_token[pos[q]] = t;
            slot_w[pos[q]] = wmem[j];
            tok_slot[base + j] = pos[q];
            pos[q]++;
        }
    }
}

// ============ 256x256 8-phase MFMA GEMM (T1+T2+T3+T4+T5, plain HIP) ============
// BK=64, 8 waves (2M x 4N), per-wave output 128x64, dbuf LDS 128 KiB split in
// half-tiles. Per K-tile: 4 phases {ds_read || stage 1 half-tile; barrier;
// lgkmcnt(0); setprio(1); 16 MFMA; setprio(0); barrier}; vmcnt(6) once per
// K-tile (3 half-tiles in flight, never drained to 0 mid-loop).
// Stage order per tile tau: B0@(tau-2).ph2, B1@(tau-2).ph3, A0@(tau-2).ph4,
// A1@(tau-1).ph1 -- each targets a region whose reads finished >=1 barrier ago.

#define BARX()  asm volatile("s_barrier" ::: "memory")
#define LGKM0() do { asm volatile("s_waitcnt lgkmcnt(0)" ::: "memory"); \
                     __builtin_amdgcn_sched_barrier(0); } while (0)
#define VMW(n)  do { asm volatile("s_waitcnt vmcnt(" #n ")" ::: "memory"); \
                     __builtin_amdgcn_sched_barrier(0); } while (0)

#define MMQ(mh, nh)                                                            \
  do {                                                                         \
    __builtin_amdgcn_sched_barrier(0);                                         \
    __builtin_amdgcn_s_setprio(1);                                             \
    _Pragma("unroll")                                                          \
    for (int mi = 0; mi < 4; ++mi)                                             \
      _Pragma("unroll")                                                        \
      for (int ni = 0; ni < 2; ++ni)                                           \
        _Pragma("unroll")                                                      \
        for (int ks = 0; ks < 2; ++ks)                                         \
          acc[(mh)*4+mi][(nh)*2+ni] = __builtin_amdgcn_mfma_f32_16x16x32_bf16( \
              afr[(mh)*4+mi][ks], bfr[(nh)*2+ni][ks],                          \
              acc[(mh)*4+mi][(nh)*2+ni], 0, 0, 0);                             \
    __builtin_amdgcn_s_setprio(0);                                             \
    __builtin_amdgcn_sched_barrier(0);                                         \
  } while (0)

#define STAGE_A(tau, h)                                                        \
  do {                                                                         \
    const int _b = (tau) & 1;                                                  \
    __builtin_amdgcn_global_load_lds((const AS1 void*)(aptr[h][0] + (tau)*64), \
        (AS3 void*)&As[(_b*2 + (h))*8192 + tid*8], 16, 0, 0);                  \
    __builtin_amdgcn_global_load_lds((const AS1 void*)(aptr[h][1] + (tau)*64), \
        (AS3 void*)&As[(_b*2 + (h))*8192 + 4096 + tid*8], 16, 0, 0);           \
  } while (0)

#define STAGE_B(tau, h)                                                        \
  do {                                                                         \
    const int _b = (tau) & 1;                                                  \
    __builtin_amdgcn_global_load_lds((const AS1 void*)(bptr[h][0] + (tau)*64), \
        (AS3 void*)&Bs[(_b*2 + (h))*8192 + tid*8], 16, 0, 0);                  \
    __builtin_amdgcn_global_load_lds((const AS1 void*)(bptr[h][1] + (tau)*64), \
        (AS3 void*)&Bs[(_b*2 + (h))*8192 + 4096 + tid*8], 16, 0, 0);           \
  } while (0)

// EPI: 0 = SwiGLU pair -> Hout bf16 [M, 512]; 1 = plain fp32 write to out;
//      2 = weighted write yr[m][c] = slot_w[m]*acc (bf16, skip pads);
//      3 = fused combine out[m][c] = acc + yr[s0][c] + yr[s1][c];
//      4 = atomicAdd fallback.
template<int KDIM, int EPI, bool GATHER, typename YT>
__global__ __launch_bounds__(512, 2) void gemm8_kernel(
    const __bf16* __restrict__ A, const __bf16* __restrict__ Bmat,
    const int* __restrict__ offs, const int* __restrict__ slot_token,
    const float* __restrict__ slot_w, const int* __restrict__ tok_slot,
    YT* __restrict__ yr,
    __bf16* __restrict__ Hout, float* __restrict__ out,
    const __bf16* __restrict__ zpage) {
    constexpr int NKT = KDIM / 64;
    // T1: bijective XCD remap (m204), N-fastest so A-panel sharers co-reside.
    const int nwg = gridDim.x;
    const int q8 = nwg >> 3, r8 = nwg & 7;
    const int xcd = blockIdx.x & 7, jj = blockIdx.x >> 3;
    const int L = (xcd < r8 ? xcd * (q8 + 1) : r8 * (q8 + 1) + (xcd - r8) * q8) + jj;
    const int tileN = L & 3;          // 4 N-tiles of 256 (N = 1024)
    const int tileM = L >> 2;
    const int tid = threadIdx.x, lane = tid & 63, wid = tid >> 6;
    const int wm = wid >> 2, wn = wid & 3;   // 2 x 4 waves

    __shared__ __bf16 As[2 * 2 * 8192];   // [buf][half][128 rows][64 k]
    __shared__ __bf16 Bs[2 * 2 * 8192];

    // per-tile expert B selection (segments 256-aligned; offs[7]=CAP = shared)
    const __bf16* Bp = Bmat;
    if (offs) {
        int m0 = tileM * 256, e = 0;
        #pragma unroll
        for (int i = 1; i < NEXP + 1; ++i) if (m0 >= offs[i]) e = i;
        Bp = Bmat + (size_t)e * (1024 * KDIM);
    }

    // staging pointers: thread stages rows rh = (tid + l*512)>>3 of each half,
    // 16B slot q = tid&7, T2-swizzled source (q ^ (rh&7)).
    const __bf16* aptr[2][2];
    const __bf16* bptr[2][2];
    #pragma unroll
    for (int h = 0; h < 2; ++h)
        #pragma unroll
        for (int l = 0; l < 2; ++l) {
            const int i = tid + l * 512;
            const int rh = i >> 3;
            const int swzo = (((tid & 7) ^ (rh & 7)) << 3);
            const int ra = tileM * 256 + h * 128 + rh;
            if (GATHER) {
                int tok = slot_token[ra];
                aptr[h][l] = (tok >= 0 ? A + (size_t)tok * KDIM : zpage) + swzo;
            } else {
                aptr[h][l] = A + (size_t)ra * KDIM + swzo;
            }
            const int rbg = tileN * 256 + h * 128 + rh;
            bptr[h][l] = Bp + (size_t)rbg * KDIM + swzo;
        }

    // read-side address constants
    const int kko0 = (((lane >> 4) ^ (lane & 7)) << 3);          // ks=0
    const int kko1 = (((4 + (lane >> 4)) ^ (lane & 7)) << 3);    // ks=1
    const int arow = (lane & 15) * 64;
    const int abase0 = (0 * 2 + wm) * 8192 + arow;
    const int abase1 = (1 * 2 + wm) * 8192 + arow;
    const int bbase0 = (0 * 2 + (wn >> 1)) * 8192 + (wn & 1) * 4096 + arow;
    const int bbase1 = (1 * 2 + (wn >> 1)) * 8192 + (wn & 1) * 4096 + arow;

    f32x4 acc[8][4] = {};
    v8bf afr[8][2], bfr[4][2];

    // ---- prologue: tile0 all 4 halves + tile1 {B0,B1,A0}; vmcnt(6) => tile0 in.
    STAGE_B(0, 0); STAGE_B(0, 1); STAGE_A(0, 0); STAGE_A(0, 1);
    STAGE_B(1, 0); STAGE_B(1, 1); STAGE_A(1, 0);
    VMW(6);
    BARX();

    #pragma unroll 2
    for (int t = 0; t < NKT; ++t) {
        const int ab = ((t & 1) ? abase1 : abase0);
        const int bb = ((t & 1) ? bbase1 : bbase0);
        // ---- phase 1: read A[0..3] + all B; stage (t+1).A1
        #pragma unroll
        for (int mi = 0; mi < 4; ++mi) {
            afr[mi][0] = *(const v8bf*)&As[ab + mi * 1024 + kko0];
            afr[mi][1] = *(const v8bf*)&As[ab + mi * 1024 + kko1];
        }
        #pragma unroll
        for (int ni = 0; ni < 4; ++ni) {
            bfr[ni][0] = *(const v8bf*)&Bs[bb + ni * 1024 + kko0];
            bfr[ni][1] = *(const v8bf*)&Bs[bb + ni * 1024 + kko1];
        }
        if (t + 1 < NKT) STAGE_A(t + 1, 1);
        BARX();
        LGKM0();
        MMQ(0, 0);
        BARX();
        // ---- phase 2: read A[4..7]; stage (t+2).B0
        #pragma unroll
        for (int mi = 4; mi < 8; ++mi) {
            afr[mi][0] = *(const v8bf*)&As[ab + mi * 1024 + kko0];
            afr[mi][1] = *(const v8bf*)&As[ab + mi * 1024 + kko1];
        }
        if (t + 2 < NKT) STAGE_B(t + 2, 0);
        BARX();
        LGKM0();
        MMQ(1, 0);
        BARX();
        // ---- phase 3: stage (t+2).B1
        if (t + 2 < NKT) STAGE_B(t + 2, 1);
        BARX();
        MMQ(0, 1);
        BARX();
        // ---- phase 4: stage (t+2).A0; counted vmcnt => tile t+1 resident
        if (t + 2 < NKT) {
            STAGE_A(t + 2, 0);
            VMW(6);
        } else if (t + 1 < NKT) {
            VMW(0);
        }
        BARX();
        MMQ(1, 1);
        BARX();
    }

    // ---- epilogue: C/D layout col = lane&15, row = (lane>>4)*4 + reg
    const int mbase = tileM * 256 + wm * 128;
    const int nbase = tileN * 256 + wn * 64;
    const int rowoff = (lane >> 4) * 4;
    const int col = lane & 15;

    if constexpr (EPI == 0) {
        #pragma unroll
        for (int mi = 0; mi < 8; ++mi)
            #pragma unroll
            for (int pi = 0; pi < 2; ++pi) {
                int ni = pi * 2;
                int hcol = (((nbase + ni * 16) >> 5) << 4) + col;
                #pragma unroll
                for (int j = 0; j < 4; ++j) {
                    int m = mbase + mi * 16 + rowoff + j;
                    float g = acc[mi][ni][j];
                    float u = acc[mi][ni + 1][j];
                    float h = (g / (1.f + __expf(-g))) * u;   // silu(g)*u
                    Hout[(size_t)m * IFF + hcol] = (__bf16)h;
                }
            }
    } else if constexpr (EPI == 1) {
        #pragma unroll
        for (int mi = 0; mi < 8; ++mi)
            #pragma unroll
            for (int j = 0; j < 4; ++j) {
                int m = mbase + mi * 16 + rowoff + j;
                #pragma unroll
                for (int ni = 0; ni < 4; ++ni)
                    out[(size_t)m * DTOK + nbase + ni * 16 + col] = acc[mi][ni][j];
            }
    } else if constexpr (EPI == 2) {
        #pragma unroll
        for (int mi = 0; mi < 8; ++mi)
            #pragma unroll
            for (int j = 0; j < 4; ++j) {
                int m = mbase + mi * 16 + rowoff + j;
                if (slot_token[m] < 0) continue;
                float wgt = slot_w[m];
                #pragma unroll
                for (int ni = 0; ni < 4; ++ni)
                    yr[(size_t)m * DTOK + nbase + ni * 16 + col] = (YT)(wgt * acc[mi][ni][j]);
            }
    } else if constexpr (EPI == 3) {
        #pragma unroll
        for (int mi = 0; mi < 8; ++mi)
            #pragma unroll
            for (int j = 0; j < 4; ++j) {
                int m = mbase + mi * 16 + rowoff + j;
                int s0 = tok_slot[2 * m], s1 = tok_slot[2 * m + 1];
                const YT* y0 = yr + (size_t)s0 * DTOK;
                const YT* y1 = yr + (size_t)s1 * DTOK;
                #pragma unroll
                for (int ni = 0; ni < 4; ++ni) {
                    int c = nbase + ni * 16 + col;
                    out[(size_t)m * DTOK + c] = acc[mi][ni][j] + (float)y0[c] + (float)y1[c];
                }
            }
    } else {  // EPI == 4: atomic fallback
        #pragma unroll
        for (int mi = 0; mi < 8; ++mi)
            #pragma unroll
            for (int j = 0; j < 4; ++j) {
                int m = mbase + mi * 16 + rowoff + j;
                int tok = slot_token[m];
                if (tok < 0) continue;
                float wgt = slot_w[m];
                #pragma unroll
                for (int ni = 0; ni < 4; ++ni)
                    atomicAdd(out + (size_t)tok * DTOK + nbase + ni * 16 + col, wgt * acc[mi][ni][j]);
            }
    }
}

// ---------------- launcher ----------------
extern "C" void kernel_launch(void* const* d_in, const int* in_sizes, int n_in,
                              void* d_out, int out_size, void* d_ws, size_t ws_size,
                              hipStream_t stream) {
    const float* x       = (const float*)d_in[0];
    const float* sh_gate = (const float*)d_in[1];
    const float* sh_up   = (const float*)d_in[2];
    const float* sh_down = (const float*)d_in[3];
    const float* r_gate  = (const float*)d_in[4];
    const float* r_up    = (const float*)d_in[5];
    const float* r_down  = (const float*)d_in[6];
    const float* w_r     = (const float*)d_in[7];
    const float* b_r     = (const float*)d_in[8];
    const float* rb      = (const float*)d_in[9];
    float* out = (float*)d_out;

    char* w = (char*)d_ws;
    __bf16* xb = (__bf16*)w;          w += (size_t)TTOK * DTOK * 2;            // 33.55 MB
    __bf16* B1 = (__bf16*)w;          w += (size_t)8 * 1024 * 1024 * 2;        // 16.78 MB
    __bf16* B2 = (__bf16*)w;          w += (size_t)8 * 1024 * 512 * 2;         //  8.39 MB
    __bf16* H  = (__bf16*)w;          w += (size_t)CAPX * IFF * 2;             // 52.2 MB (routed | shared)
    int*    top_i = (int*)w;          w += (size_t)TTOK * 2 * 4;
    float*  top_w = (float*)w;        w += (size_t)TTOK * 2 * 4;
    int*    slot_token = (int*)w;     w += (size_t)CAPX * 4;
    float*  slot_w = (float*)w;       w += (size_t)CAPX * 4;
    int*    tok_slot = (int*)w;       w += (size_t)TTOK * 2 * 4;
    int*    offs = (int*)w;           w += 256;
    __bf16* zpage = (__bf16*)w;       w += 4096;
    void*   Yr = (void*)w;
    size_t used = (size_t)(w - (char*)d_ws);
    size_t rem = (ws_size > used) ? (ws_size - used) : 0;
    bool have_yr = rem >= (size_t)CAP * DTOK * 2;   // bf16 Yr = 70.8 MB

    init_kernel<<<(CAPX + 255) / 256, 256, 0, stream>>>(slot_token, slot_w, zpage);
    cast_x_kernel<<<(TTOK * DTOK / 4) / 256, 256, 0, stream>>>((const float4*)x, xb);
    build_B1t<<<dim3(2, 32, 8), 256, 0, stream>>>(r_gate, r_up, sh_gate, sh_up, B1);
    build_B2t<<<dim3(2, 16, 8), 256, 0, stream>>>(r_down, sh_down, B2);
    router_kernel<<<TTOK / 4, 256, 0, stream>>>(x, w_r, b_r, rb, top_i, top_w);
    gather_kernel<<<1, 1024, 0, stream>>>(top_i, top_w, slot_token, slot_w, tok_slot, offs);

    dim3 blk(512);
    // GEMM1 merged (routed + shared): gathered A rows, per-segment expert B, -> H
    gemm8_kernel<DTOK, 0, true, __bf16><<<(CAPX / 256) * 4, blk, 0, stream>>>(
        xb, B1, offs, slot_token, nullptr, nullptr, nullptr, H, nullptr, zpage);

    if (have_yr) {
        __bf16* yr = (__bf16*)Yr;
        // GEMM2 routed: H[0..CAP) x down^T -> yr = w * y (bf16)
        gemm8_kernel<IFF, 2, false, __bf16><<<(CAP / 256) * 4, blk, 0, stream>>>(
            H, B2, offs, slot_token, slot_w, nullptr, yr, nullptr, nullptr, zpage);
        // GEMM2 shared+combine: H[CAP..) x down7^T; out = acc + yr[s0] + yr[s1]
        gemm8_kernel<IFF, 3, false, __bf16><<<(TTOK / 256) * 4, blk, 0, stream>>>(
            H + (size_t)CAP * IFF, B2 + (size_t)NEXP * 1024 * 512,
            nullptr, nullptr, nullptr, tok_slot, yr, nullptr, out, zpage);
    } else {
        // fallback: shared plain write, routed atomic accumulate
        gemm8_kernel<IFF, 1, false, __bf16><<<(TTOK / 256) * 4, blk, 0, stream>>>(
            H + (size_t)CAP * IFF, B2 + (size_t)NEXP * 1024 * 512,
            nullptr, nullptr, nullptr, nullptr, nullptr, nullptr, out, zpage);
        gemm8_kernel<IFF, 4, false, __bf16><<<(CAP / 256) * 4, blk, 0, stream>>>(
            H, B2, offs, slot_token, slot_w, nullptr, nullptr, nullptr, out, zpage);
    }
}

// Round 7
// 408.457 us; speedup vs baseline: 1.2685x; 1.2685x over previous
//
#include <hip/hip_runtime.h>
#include <hip/hip_bf16.h>
#include <cstdint>
#include <cstddef>

// ---------------- problem constants ----------------
#define DTOK 1024      // embed dim
#define IFF  512       // ffn intermediate
#define NEXP 7         // routed experts
#define TTOK 16384     // B*S tokens
#define CAP  (2*TTOK + NEXP*256)   // padded routed slot capacity = 34560 (135 tiles of 256)
#define CAPX (CAP + TTOK)          // + shared segment (expert 7, identity) = 50944

typedef __bf16 v8bf  __attribute__((ext_vector_type(8)));
typedef float  f32x4 __attribute__((ext_vector_type(4)));

#define AS1 __attribute__((address_space(1)))
#define AS3 __attribute__((address_space(3)))

// ---------------- small prep kernels ----------------

// slots [0,CAP): routed (filled by gather); [CAP,CAPX): shared expert, identity map, w=1
__global__ void init_kernel(int* __restrict__ slot_token, float* __restrict__ slot_w,
                            __bf16* __restrict__ zpage) {
    int i = blockIdx.x * 256 + threadIdx.x;
    if (i < CAP) slot_token[i] = -1;
    else if (i < CAPX) { slot_token[i] = i - CAP; slot_w[i] = 1.f; }
    if (i < 2048) zpage[i] = (__bf16)0.f;
}

__global__ void cast_x_kernel(const float4* __restrict__ x, __bf16* __restrict__ xb) {
    int i = blockIdx.x * 256 + threadIdx.x;   // one float4 per thread
    float4 v = x[i];
    typedef __bf16 v4bf __attribute__((ext_vector_type(4)));
    v4bf o; o[0] = (__bf16)v.x; o[1] = (__bf16)v.y; o[2] = (__bf16)v.z; o[3] = (__bf16)v.w;
    *reinterpret_cast<v4bf*>(xb + (size_t)i * 4) = o;
}

// B1[e][r][k] = W[k][c], c=(r>>5)*16+(r&15), gate if (r&31)<16 else up.
// Coalesced via LDS transpose. block = (kh in [0,2), j in [0,32), e in [0,8))
__global__ __launch_bounds__(256) void build_B1t(
    const float* __restrict__ r_gate, const float* __restrict__ r_up,
    const float* __restrict__ sh_gate, const float* __restrict__ sh_up,
    __bf16* __restrict__ B1) {
    const int kh = blockIdx.x, j = blockIdx.y, e = blockIdx.z;
    const float* G = (e < NEXP) ? (r_gate + (size_t)e * (DTOK * IFF)) : sh_gate;
    const float* U = (e < NEXP) ? (r_up   + (size_t)e * (DTOK * IFF)) : sh_up;
    __shared__ __bf16 lg[16][520];
    __shared__ __bf16 lu[16][520];
    const int tid = threadIdx.x;
    const int c4 = tid & 3, kk0 = tid >> 2;
    #pragma unroll
    for (int p = 0; p < 8; ++p) {
        int kk = kk0 + p * 64;
        size_t off = (size_t)(kh * 512 + kk) * IFF + j * 16 + c4 * 4;
        float4 g = *(const float4*)&G[off];
        float4 u = *(const float4*)&U[off];
        lg[c4*4+0][kk] = (__bf16)g.x; lg[c4*4+1][kk] = (__bf16)g.y;
        lg[c4*4+2][kk] = (__bf16)g.z; lg[c4*4+3][kk] = (__bf16)g.w;
        lu[c4*4+0][kk] = (__bf16)u.x; lu[c4*4+1][kk] = (__bf16)u.y;
        lu[c4*4+2][kk] = (__bf16)u.z; lu[c4*4+3][kk] = (__bf16)u.w;
    }
    __syncthreads();
    const int rr = tid >> 3;
    const int ch0 = tid & 7;
    const int cc = rr & 15;
    const bool isup = rr >= 16;
    const int r = j * 32 + (isup ? 16 : 0) + cc;
    const __bf16* src = isup ? &lu[cc][0] : &lg[cc][0];
    __bf16* dst = B1 + ((size_t)e << 20) + (size_t)r * DTOK + kh * 512;
    #pragma unroll
    for (int q = 0; q < 8; ++q) {
        int ch = ch0 + q * 8;
        *(v8bf*)&dst[ch * 8] = *(const v8bf*)&src[ch * 8];
    }
}

// B2[e][n][k] = down[k][n]. block = (kh in [0,2), nb in [0,16), e in [0,8))
__global__ __launch_bounds__(256) void build_B2t(
    const float* __restrict__ r_down, const float* __restrict__ sh_down,
    __bf16* __restrict__ B2) {
    const int kh = blockIdx.x, nb = blockIdx.y, e = blockIdx.z;
    const float* D = (e < NEXP) ? (r_down + (size_t)e * (IFF * DTOK)) : sh_down;
    __shared__ __bf16 ln[64][264];
    const int tid = threadIdx.x;
    const int c4 = tid & 15, kk0 = tid >> 4;
    #pragma unroll
    for (int p = 0; p < 16; ++p) {
        int kk = kk0 + p * 16;
        size_t off = (size_t)(kh * 256 + kk) * DTOK + nb * 64 + c4 * 4;
        float4 v = *(const float4*)&D[off];
        ln[c4*4+0][kk] = (__bf16)v.x; ln[c4*4+1][kk] = (__bf16)v.y;
        ln[c4*4+2][kk] = (__bf16)v.z; ln[c4*4+3][kk] = (__bf16)v.w;
    }
    __syncthreads();
    const int nn = tid >> 2;
    const int ch0 = tid & 3;
    __bf16* dst = B2 + ((size_t)e * 1024 + nb * 64 + nn) * IFF + kh * 256;
    #pragma unroll
    for (int q = 0; q < 8; ++q) {
        int ch = ch0 + q * 4;
        *(v8bf*)&dst[ch * 8] = *(const v8bf*)&ln[nn][ch * 8];
    }
}

// Router: full fp32 (bf16 x would flip near-tie top-k picks -> real output error).
__global__ __launch_bounds__(256) void router_kernel(
    const float* __restrict__ x, const float* __restrict__ w_r,
    const float* __restrict__ b_r, const float* __restrict__ rb,
    int* __restrict__ top_i, float* __restrict__ top_w) {
    int wid = threadIdx.x >> 6, lane = threadIdx.x & 63;
    int t = blockIdx.x * 4 + wid;
    float acc[NEXP] = {0.f,0.f,0.f,0.f,0.f,0.f,0.f};
    #pragma unroll 4
    for (int it = 0; it < DTOK / 64; ++it) {
        int d = it * 64 + lane;
        float xv = x[(size_t)t * DTOK + d];
        const float* wr = w_r + (size_t)d * NEXP;
        #pragma unroll
        for (int e = 0; e < NEXP; ++e) acc[e] += xv * wr[e];
    }
    #pragma unroll
    for (int e = 0; e < NEXP; ++e)
        #pragma unroll
        for (int off = 32; off; off >>= 1) acc[e] += __shfl_xor(acc[e], off);
    if (lane == 0) {
        float p[NEXP];
        #pragma unroll
        for (int e = 0; e < NEXP; ++e) p[e] = 1.f / (1.f + expf(-(acc[e] + b_r[e] + rb[e])));
        int i0 = 0;
        #pragma unroll
        for (int e = 1; e < NEXP; ++e) if (p[e] > p[i0]) i0 = e;
        int i1 = -1;
        #pragma unroll
        for (int e = 0; e < NEXP; ++e) if (e != i0 && (i1 < 0 || p[e] > p[i1])) i1 = e;
        float s = p[i0] + p[i1];
        top_i[2 * t] = i0; top_i[2 * t + 1] = i1;
        top_w[2 * t] = p[i0] / s; top_w[2 * t + 1] = p[i1] / s;
    }
}

// Deterministic atomic-free gather build (scan). Segments padded to 256 rows.
__global__ __launch_bounds__(1024) void gather_kernel(
    const int* __restrict__ top_i, const float* __restrict__ top_w,
    int* __restrict__ slot_token, float* __restrict__ slot_w,
    int* __restrict__ tok_slot, int* __restrict__ offs_out) {
    __shared__ int h[NEXP][1024];
    __shared__ int lofs[NEXP];
    const int tid = threadIdx.x;
    const int base = tid * 32;

    int cnt[NEXP] = {0,0,0,0,0,0,0};
    int emem[32];
    float wmem[32];
    #pragma unroll
    for (int j = 0; j < 32; ++j) {
        emem[j] = top_i[base + j];
        wmem[j] = top_w[base + j];
        #pragma unroll
        for (int q = 0; q < NEXP; ++q) if (emem[j] == q) cnt[q]++;
    }
    #pragma unroll
    for (int q = 0; q < NEXP; ++q) h[q][tid] = cnt[q];
    __syncthreads();
    for (int off = 1; off < 1024; off <<= 1) {
        int v[NEXP];
        #pragma unroll
        for (int q = 0; q < NEXP; ++q) v[q] = (tid >= off) ? h[q][tid - off] : 0;
        __syncthreads();
        #pragma unroll
        for (int q = 0; q < NEXP; ++q) h[q][tid] += v[q];
        __syncthreads();
    }
    if (tid == 0) {
        int o = 0;
        #pragma unroll
        for (int q = 0; q < NEXP; ++q) { lofs[q] = o; o += ((h[q][1023] + 255) >> 8) << 8; }
        #pragma unroll
        for (int q = 0; q < NEXP; ++q) offs_out[q] = lofs[q];
        offs_out[NEXP] = CAP;   // expert 7 = shared segment
    }
    __syncthreads();
    int pos[NEXP];
    #pragma unroll
    for (int q = 0; q < NEXP; ++q) pos[q] = lofs[q] + h[q][tid] - cnt[q];
    #pragma unroll
    for (int j = 0; j < 32; ++j) {
        int t = (base + j) >> 1;
        #pragma unroll
        for (int q = 0; q < NEXP; ++q) if (emem[j] == q) {
            slot_token[pos[q]] = t;
            slot_w[pos[q]] = wmem[j];
            tok_slot[base + j] = pos[q];
            pos[q]++;
        }
    }
}

// ============ 256x256 8-phase MFMA GEMM (T1+T2+T3+T4+T5, plain HIP) ============
// BK=64, 8 waves (2M x 4N), dbuf LDS 128 KiB. Register-budgeted: afr[8][2] +
// transient bfr[2][2] + 128 acc AGPR ~= 244 unified < 256 @ 2 waves/SIMD.
//
// RACE-SAFE STAGING (round-6 lesson): tile t+2 shares the buffer with tile t,
// so a stage into region R may only issue in the phase AFTER the phase whose
// lgkmcnt(0) drained the last read of R for tile t:
//   A reads drain at ph2 -> stage A0(t+2) in ph3;
//   B reads drain at ph3 -> stage B0(t+2)+B1(t+2) in ph4;
//   A1(t+1) (opposite buffer) stays in ph1.
// vmcnt: outstanding before ph4 wait = 14, oldest 8 = tile t+1 -> vmcnt(6).

#define BARX()  asm volatile("s_barrier" ::: "memory")
#define LGKM0() do { asm volatile("s_waitcnt lgkmcnt(0)" ::: "memory"); \
                     __builtin_amdgcn_sched_barrier(0); } while (0)
#define VMW(n)  do { asm volatile("s_waitcnt vmcnt(" #n ")" ::: "memory"); \
                     __builtin_amdgcn_sched_barrier(0); } while (0)

// quadrant (mh, nh): acc rows mh*4.., cols nh*2..; B operand always bfr[0..1]
#define MMQ(mh, nh)                                                            \
  do {                                                                         \
    __builtin_amdgcn_sched_barrier(0);                                         \
    __builtin_amdgcn_s_setprio(1);                                             \
    _Pragma("unroll")                                                          \
    for (int mi = 0; mi < 4; ++mi)                                             \
      _Pragma("unroll")                                                        \
      for (int nj = 0; nj < 2; ++nj)                                           \
        _Pragma("unroll")                                                      \
        for (int ks = 0; ks < 2; ++ks)                                         \
          acc[(mh)*4+mi][(nh)*2+nj] = __builtin_amdgcn_mfma_f32_16x16x32_bf16( \
              afr[(mh)*4+mi][ks], bfr[nj][ks],                                 \
              acc[(mh)*4+mi][(nh)*2+nj], 0, 0, 0);                             \
    __builtin_amdgcn_s_setprio(0);                                             \
    __builtin_amdgcn_sched_barrier(0);                                         \
  } while (0)

#define READ_A(mh)                                                             \
  do {                                                                         \
    _Pragma("unroll")                                                          \
    for (int mi = 0; mi < 4; ++mi) {                                           \
      afr[(mh)*4+mi][0] = *(const v8bf*)&As[ab + ((mh)*4+mi)*1024 + kko0];     \
      afr[(mh)*4+mi][1] = *(const v8bf*)&As[ab + ((mh)*4+mi)*1024 + kko1];     \
    }                                                                          \
  } while (0)

#define READ_B(nh)                                                             \
  do {                                                                         \
    _Pragma("unroll")                                                          \
    for (int nj = 0; nj < 2; ++nj) {                                           \
      bfr[nj][0] = *(const v8bf*)&Bs[bb + ((nh)*2+nj)*1024 + kko0];            \
      bfr[nj][1] = *(const v8bf*)&Bs[bb + ((nh)*2+nj)*1024 + kko1];            \
    }                                                                          \
  } while (0)

#define STAGE_A(tau, h)                                                        \
  do {                                                                         \
    const int _b = (tau) & 1;                                                  \
    __builtin_amdgcn_global_load_lds((const AS1 void*)(aptr[h][0] + (tau)*64), \
        (AS3 void*)&As[(_b*2 + (h))*8192 + tid*8], 16, 0, 0);                  \
    __builtin_amdgcn_global_load_lds((const AS1 void*)(aptr[h][1] + (tau)*64), \
        (AS3 void*)&As[(_b*2 + (h))*8192 + 4096 + tid*8], 16, 0, 0);           \
  } while (0)

#define STAGE_B(tau, h)                                                        \
  do {                                                                         \
    const int _b = (tau) & 1;                                                  \
    __builtin_amdgcn_global_load_lds((const AS1 void*)(bptr[h][0] + (tau)*64), \
        (AS3 void*)&Bs[(_b*2 + (h))*8192 + tid*8], 16, 0, 0);                  \
    __builtin_amdgcn_global_load_lds((const AS1 void*)(bptr[h][1] + (tau)*64), \
        (AS3 void*)&Bs[(_b*2 + (h))*8192 + 4096 + tid*8], 16, 0, 0);           \
  } while (0)

// EPI: 0 = SwiGLU pair -> Hout bf16 [M, 512]; 1 = plain fp32 write to out;
//      2 = weighted write yr[m][c] = slot_w[m]*acc (bf16, skip pads);
//      3 = fused combine out[m][c] = acc + yr[s0][c] + yr[s1][c];
//      4 = atomicAdd fallback.
template<int KDIM, int EPI, bool GATHER, typename YT>
__global__ __launch_bounds__(512, 2) void gemm8_kernel(
    const __bf16* __restrict__ A, const __bf16* __restrict__ Bmat,
    const int* __restrict__ offs, const int* __restrict__ slot_token,
    const float* __restrict__ slot_w, const int* __restrict__ tok_slot,
    YT* __restrict__ yr,
    __bf16* __restrict__ Hout, float* __restrict__ out,
    const __bf16* __restrict__ zpage) {
    constexpr int NKT = KDIM / 64;
    // T1: bijective XCD remap (m204), N-fastest so A-panel sharers co-reside.
    const int nwg = gridDim.x;
    const int q8 = nwg >> 3, r8 = nwg & 7;
    const int xcd = blockIdx.x & 7, jj = blockIdx.x >> 3;
    const int L = (xcd < r8 ? xcd * (q8 + 1) : r8 * (q8 + 1) + (xcd - r8) * q8) + jj;
    const int tileN = L & 3;          // 4 N-tiles of 256 (N = 1024)
    const int tileM = L >> 2;
    const int tid = threadIdx.x, lane = tid & 63, wid = tid >> 6;
    const int wm = wid >> 2, wn = wid & 3;   // 2 x 4 waves

    __shared__ __bf16 As[2 * 2 * 8192];   // [buf][half][128 rows][64 k]
    __shared__ __bf16 Bs[2 * 2 * 8192];

    // per-tile expert B selection (segments 256-aligned; offs[7]=CAP = shared)
    const __bf16* Bp = Bmat;
    if (offs) {
        int m0 = tileM * 256, e = 0;
        #pragma unroll
        for (int i = 1; i < NEXP + 1; ++i) if (m0 >= offs[i]) e = i;
        Bp = Bmat + (size_t)e * (1024 * KDIM);
    }

    // staging pointers: thread stages rows rh = (tid + l*512)>>3 of each half,
    // 16B slot q = tid&7, T2-swizzled source (q ^ (rh&7)).
    const __bf16* aptr[2][2];
    const __bf16* bptr[2][2];
    #pragma unroll
    for (int h = 0; h < 2; ++h)
        #pragma unroll
        for (int l = 0; l < 2; ++l) {
            const int i = tid + l * 512;
            const int rh = i >> 3;
            const int swzo = (((tid & 7) ^ (rh & 7)) << 3);
            const int ra = tileM * 256 + h * 128 + rh;
            if (GATHER) {
                int tok = slot_token[ra];
                aptr[h][l] = (tok >= 0 ? A + (size_t)tok * KDIM : zpage) + swzo;
            } else {
                aptr[h][l] = A + (size_t)ra * KDIM + swzo;
            }
            const int rbg = tileN * 256 + h * 128 + rh;
            bptr[h][l] = Bp + (size_t)rbg * KDIM + swzo;
        }

    // read-side address constants
    const int kko0 = (((lane >> 4) ^ (lane & 7)) << 3);          // ks=0
    const int kko1 = (((4 + (lane >> 4)) ^ (lane & 7)) << 3);    // ks=1
    const int arow = (lane & 15) * 64;

    f32x4 acc[8][4] = {};
    v8bf afr[8][2];
    v8bf bfr[2][2];

    // ---- prologue: tile0 (8 loads) + tile1 {A0, B0, B1} in steady-state
    // issue order; vmcnt(6) => tile0 resident.
    STAGE_B(0, 0); STAGE_B(0, 1); STAGE_A(0, 0); STAGE_A(0, 1);
    STAGE_A(1, 0); STAGE_B(1, 0); STAGE_B(1, 1);
    VMW(6);
    BARX();

    #pragma unroll 2
    for (int t = 0; t < NKT; ++t) {
        const int ab = ((t & 1) * 2 + wm) * 8192 + arow;
        const int bb = ((t & 1) * 2 + (wn >> 1)) * 8192 + (wn & 1) * 4096 + arow;
        // ---- phase 1: read A-half0 (8) + B-n0 (4); stage (t+1).A1 (other buf)
        READ_A(0);
        READ_B(0);
        if (t + 1 < NKT) STAGE_A(t + 1, 1);
        BARX();
        LGKM0();
        MMQ(0, 0);
        BARX();
        // ---- phase 2: read A-half1 (8); NO staging (A region not yet drained)
        READ_A(1);
        BARX();
        LGKM0();
        MMQ(1, 0);
        BARX();
        // ---- phase 3: read B-n1 (4, reuses bfr regs); stage (t+2).A0
        //      (A reads of tile t drained at ph2's lgkmcnt(0))
        READ_B(1);
        if (t + 2 < NKT) STAGE_A(t + 2, 0);
        BARX();
        LGKM0();
        MMQ(0, 1);
        BARX();
        // ---- phase 4: stage (t+2).B0+B1 (B reads drained at ph3); vmcnt(6)
        if (t + 2 < NKT) {
            STAGE_B(t + 2, 0);
            STAGE_B(t + 2, 1);
            VMW(6);
        } else if (t + 1 < NKT) {
            VMW(0);
        }
        BARX();
        MMQ(1, 1);
        BARX();
    }

    // ---- epilogue: C/D layout col = lane&15, row = (lane>>4)*4 + reg
    const int mbase = tileM * 256 + wm * 128;
    const int nbase = tileN * 256 + wn * 64;
    const int rowoff = (lane >> 4) * 4;
    const int col = lane & 15;

    if constexpr (EPI == 0) {
        #pragma unroll
        for (int mi = 0; mi < 8; ++mi)
            #pragma unroll
            for (int pi = 0; pi < 2; ++pi) {
                int ni = pi * 2;
                int hcol = (((nbase + ni * 16) >> 5) << 4) + col;
                #pragma unroll
                for (int j = 0; j < 4; ++j) {
                    int m = mbase + mi * 16 + rowoff + j;
                    float g = acc[mi][ni][j];
                    float u = acc[mi][ni + 1][j];
                    float h = (g / (1.f + __expf(-g))) * u;   // silu(g)*u
                    Hout[(size_t)m * IFF + hcol] = (__bf16)h;
                }
            }
    } else if constexpr (EPI == 1) {
        #pragma unroll
        for (int mi = 0; mi < 8; ++mi)
            #pragma unroll
            for (int j = 0; j < 4; ++j) {
                int m = mbase + mi * 16 + rowoff + j;
                #pragma unroll
                for (int ni = 0; ni < 4; ++ni)
                    out[(size_t)m * DTOK + nbase + ni * 16 + col] = acc[mi][ni][j];
            }
    } else if constexpr (EPI == 2) {
        #pragma unroll
        for (int mi = 0; mi < 8; ++mi)
            #pragma unroll
            for (int j = 0; j < 4; ++j) {
                int m = mbase + mi * 16 + rowoff + j;
                if (slot_token[m] < 0) continue;
                float wgt = slot_w[m];
                #pragma unroll
                for (int ni = 0; ni < 4; ++ni)
                    yr[(size_t)m * DTOK + nbase + ni * 16 + col] = (YT)(wgt * acc[mi][ni][j]);
            }
    } else if constexpr (EPI == 3) {
        #pragma unroll
        for (int mi = 0; mi < 8; ++mi)
            #pragma unroll
            for (int j = 0; j < 4; ++j) {
                int m = mbase + mi * 16 + rowoff + j;
                int s0 = tok_slot[2 * m], s1 = tok_slot[2 * m + 1];
                const YT* y0 = yr + (size_t)s0 * DTOK;
                const YT* y1 = yr + (size_t)s1 * DTOK;
                #pragma unroll
                for (int ni = 0; ni < 4; ++ni) {
                    int c = nbase + ni * 16 + col;
                    out[(size_t)m * DTOK + c] = acc[mi][ni][j] + (float)y0[c] + (float)y1[c];
                }
            }
    } else {  // EPI == 4: atomic fallback
        #pragma unroll
        for (int mi = 0; mi < 8; ++mi)
            #pragma unroll
            for (int j = 0; j < 4; ++j) {
                int m = mbase + mi * 16 + rowoff + j;
                int tok = slot_token[m];
                if (tok < 0) continue;
                float wgt = slot_w[m];
                #pragma unroll
                for (int ni = 0; ni < 4; ++ni)
                    atomicAdd(out + (size_t)tok * DTOK + nbase + ni * 16 + col, wgt * acc[mi][ni][j]);
            }
    }
}

// ---------------- launcher ----------------
extern "C" void kernel_launch(void* const* d_in, const int* in_sizes, int n_in,
                              void* d_out, int out_size, void* d_ws, size_t ws_size,
                              hipStream_t stream) {
    const float* x       = (const float*)d_in[0];
    const float* sh_gate = (const float*)d_in[1];
    const float* sh_up   = (const float*)d_in[2];
    const float* sh_down = (const float*)d_in[3];
    const float* r_gate  = (const float*)d_in[4];
    const float* r_up    = (const float*)d_in[5];
    const float* r_down  = (const float*)d_in[6];
    const float* w_r     = (const float*)d_in[7];
    const float* b_r     = (const float*)d_in[8];
    const float* rb      = (const float*)d_in[9];
    float* out = (float*)d_out;

    char* w = (char*)d_ws;
    __bf16* xb = (__bf16*)w;          w += (size_t)TTOK * DTOK * 2;            // 33.55 MB
    __bf16* B1 = (__bf16*)w;          w += (size_t)8 * 1024 * 1024 * 2;        // 16.78 MB
    __bf16* B2 = (__bf16*)w;          w += (size_t)8 * 1024 * 512 * 2;         //  8.39 MB
    __bf16* H  = (__bf16*)w;          w += (size_t)CAPX * IFF * 2;             // 52.2 MB (routed | shared)
    int*    top_i = (int*)w;          w += (size_t)TTOK * 2 * 4;
    float*  top_w = (float*)w;        w += (size_t)TTOK * 2 * 4;
    int*    slot_token = (int*)w;     w += (size_t)CAPX * 4;
    float*  slot_w = (float*)w;       w += (size_t)CAPX * 4;
    int*    tok_slot = (int*)w;       w += (size_t)TTOK * 2 * 4;
    int*    offs = (int*)w;           w += 256;
    __bf16* zpage = (__bf16*)w;       w += 4096;
    void*   Yr = (void*)w;
    size_t used = (size_t)(w - (char*)d_ws);
    size_t rem = (ws_size > used) ? (ws_size - used) : 0;
    bool have_yr = rem >= (size_t)CAP * DTOK * 2;   // bf16 Yr = 70.8 MB

    init_kernel<<<(CAPX + 255) / 256, 256, 0, stream>>>(slot_token, slot_w, zpage);
    cast_x_kernel<<<(TTOK * DTOK / 4) / 256, 256, 0, stream>>>((const float4*)x, xb);
    build_B1t<<<dim3(2, 32, 8), 256, 0, stream>>>(r_gate, r_up, sh_gate, sh_up, B1);
    build_B2t<<<dim3(2, 16, 8), 256, 0, stream>>>(r_down, sh_down, B2);
    router_kernel<<<TTOK / 4, 256, 0, stream>>>(x, w_r, b_r, rb, top_i, top_w);
    gather_kernel<<<1, 1024, 0, stream>>>(top_i, top_w, slot_token, slot_w, tok_slot, offs);

    dim3 blk(512);
    // GEMM1 merged (routed + shared): gathered A rows, per-segment expert B, -> H
    gemm8_kernel<DTOK, 0, true, __bf16><<<(CAPX / 256) * 4, blk, 0, stream>>>(
        xb, B1, offs, slot_token, nullptr, nullptr, nullptr, H, nullptr, zpage);

    if (have_yr) {
        __bf16* yr = (__bf16*)Yr;
        // GEMM2 routed: H[0..CAP) x down^T -> yr = w * y (bf16)
        gemm8_kernel<IFF, 2, false, __bf16><<<(CAP / 256) * 4, blk, 0, stream>>>(
            H, B2, offs, slot_token, slot_w, nullptr, yr, nullptr, nullptr, zpage);
        // GEMM2 shared+combine: H[CAP..) x down7^T; out = acc + yr[s0] + yr[s1]
        gemm8_kernel<IFF, 3, false, __bf16><<<(TTOK / 256) * 4, blk, 0, stream>>>(
            H + (size_t)CAP * IFF, B2 + (size_t)NEXP * 1024 * 512,
            nullptr, nullptr, nullptr, tok_slot, yr, nullptr, out, zpage);
    } else {
        // fallback: shared plain write, routed atomic accumulate
        gemm8_kernel<IFF, 1, false, __bf16><<<(TTOK / 256) * 4, blk, 0, stream>>>(
            H + (size_t)CAP * IFF, B2 + (size_t)NEXP * 1024 * 512,
            nullptr, nullptr, nullptr, nullptr, nullptr, nullptr, out, zpage);
        gemm8_kernel<IFF, 4, false, __bf16><<<(CAP / 256) * 4, blk, 0, stream>>>(
            H, B2, offs, slot_token, slot_w, nullptr, nullptr, nullptr, out, zpage);
    }
}